// Round 3
// baseline (839.919 us; speedup 1.0000x reference)
//
#include <hip/hip_runtime.h>
#include <math.h>

#define N_NODES 50000
#define N_EDGES 1600000
#define D_IN 128
#define D_HID 128
#define D_OUT 64
#define N_EXPERT 16
#define NB 8    // nodes per block in gate/last kernels (50000 % 8 == 0)
#define GNB 64  // nodes per chunk in expert GEMM
#define NYB 16  // y-slots per expert: 16*16 = 256 blocks = 1/CU (96 KB LDS)
#define NGBLK (N_NODES / NB)   // 6250 gate blocks per layer

// ---------------- gate: logits + softmax-std + argmax ------------------------
// One block = 128 threads = NB(8) nodes. Thread (e = t&15, j = t>>4).
// Per-block std partial written to gpart[blockIdx] (NO global atomics).
__global__ __launch_bounds__(128) void gate_kernel(
    const float* __restrict__ x, const float* __restrict__ Wg, const float* __restrict__ bg,
    int* __restrict__ eidx, float* __restrict__ gpart)
{
    __shared__ float xs[NB][132];   // +4 pad: j-groups land in disjoint banks
    __shared__ float sred[NB];
    const int n0 = blockIdx.x * NB;
    const int t = threadIdx.x;

    #pragma unroll
    for (int j = 0; j < NB; ++j)
        xs[j][t] = x[(size_t)(n0 + j) * 128 + t];
    __syncthreads();

    const int e = t & 15, j = t >> 4;
    float lg = bg[e];
    #pragma unroll
    for (int d4 = 0; d4 < 32; ++d4) {   // float4 LDS reads, d-ascending order kept
        const float4 xv = *(const float4*)&xs[j][4 * d4];
        lg = fmaf(xv.x, Wg[(4 * d4 + 0) * 16 + e], lg);
        lg = fmaf(xv.y, Wg[(4 * d4 + 1) * 16 + e], lg);
        lg = fmaf(xv.z, Wg[(4 * d4 + 2) * 16 + e], lg);
        lg = fmaf(xv.w, Wg[(4 * d4 + 3) * 16 + e], lg);
    }

    // 16-lane-group reductions (lanes of one node are contiguous)
    float mx = lg;
    #pragma unroll
    for (int m = 8; m >= 1; m >>= 1) mx = fmaxf(mx, __shfl_xor(mx, m, 16));
    const float ex = expf(lg - mx);
    float se = ex;
    #pragma unroll
    for (int m = 8; m >= 1; m >>= 1) se += __shfl_xor(se, m, 16);
    const float p = ex / se;
    const float dm = p - (1.f / 16.f);
    float var = dm * dm;
    #pragma unroll
    for (int m = 8; m >= 1; m >>= 1) var += __shfl_xor(var, m, 16);

    // argmax over logits (== argmax over softmax), first-index on ties
    float bv = lg; int bi = e;
    #pragma unroll
    for (int m = 8; m >= 1; m >>= 1) {
        const float ov = __shfl_xor(bv, m, 16);
        const int oi = __shfl_xor(bi, m, 16);
        if (ov > bv || (ov == bv && oi < bi)) { bv = ov; bi = oi; }
    }
    if (e == 0) {
        eidx[n0 + j] = bi;
        sred[j] = sqrtf(var * (1.f / 15.f));
    }
    __syncthreads();
    if (t == 0) {
        float s = 0.f;
        #pragma unroll
        for (int jj = 0; jj < NB; ++jj) s += sred[jj];
        gpart[blockIdx.x] = s;
    }
}

// ---------------- expert bucketing: hist16 -> scan16 -> scatter16 ------------
__global__ __launch_bounds__(256) void hist16_kernel(
    const int* __restrict__ eidx, int* __restrict__ ecnt)
{
    __shared__ int lcnt[N_EXPERT];
    const int t = threadIdx.x;
    const int n = blockIdx.x * 256 + t;
    if (t < N_EXPERT) lcnt[t] = 0;
    __syncthreads();
    if (n < N_NODES) atomicAdd(&lcnt[eidx[n]], 1);
    __syncthreads();
    if (t < N_EXPERT && lcnt[t] > 0) atomicAdd(&ecnt[t], lcnt[t]);
}

__global__ void scan16_kernel(const int* __restrict__ ecnt,
                              int* __restrict__ eoff, int* __restrict__ ecur)
{
    if (threadIdx.x == 0) {
        int s = 0;
        #pragma unroll
        for (int e = 0; e < N_EXPERT; ++e) { eoff[e] = s; ecur[e] = s; s += ecnt[e]; }
        eoff[N_EXPERT] = s;
    }
}

__global__ __launch_bounds__(256) void scatter16_kernel(
    const int* __restrict__ eidx, int* __restrict__ ecur, int* __restrict__ elist)
{
    __shared__ int lcnt[N_EXPERT];
    __shared__ int lbase[N_EXPERT];
    const int t = threadIdx.x;
    const int n = blockIdx.x * 256 + t;
    if (t < N_EXPERT) lcnt[t] = 0;
    __syncthreads();
    int e = 0, lpos = 0;
    if (n < N_NODES) { e = eidx[n]; lpos = atomicAdd(&lcnt[e], 1); }
    __syncthreads();
    if (t < N_EXPERT && lcnt[t] > 0) lbase[t] = atomicAdd(&ecur[t], lcnt[t]);
    __syncthreads();
    if (n < N_NODES) elist[lbase[e] + lpos] = n;
}

// ---------------- per-expert GEMM: y[n] = x[n] @ We[e] + be[e] ---------------
// grid = (16 experts, NYB=16) = 256 blocks = exactly 1 per CU (96 KB LDS).
// Each block chunk-strides over its expert's chunks (~3-4 each): the 64 KB
// W-stage is amortized, and next chunk's x is prefetched into registers
// during the current chunk's compute (T14 issue-early/write-late).
// 256 threads: thread (dg = t&31 -> dims 4dg..4dg+3, ng = t>>5 -> nodes 8ng..8ng+7).
__global__ __launch_bounds__(256) void expert_gemm_kernel(
    const float* __restrict__ x, const float* __restrict__ We, const float* __restrict__ be,
    const int* __restrict__ eoff, const int* __restrict__ elist, float* __restrict__ y)
{
    __shared__ float Ws[128 * 128];   // 64 KB
    __shared__ float xsd[GNB * 128];  // 32 KB
    const int e = blockIdx.x;
    const int t = threadIdx.x;
    const int row0 = eoff[e];
    const int row1 = eoff[e + 1];
    int start = row0 + (int)blockIdx.y * GNB;
    if (start >= row1) return;  // block-uniform early exit

    // stage We[e] into LDS: linear float4 copy, coalesced + conflict-free
    {
        const float4* __restrict__ Wg4 = (const float4*)(We + (size_t)e * 16384);
        float4* Ws4 = (float4*)Ws;
        #pragma unroll
        for (int i = 0; i < 16; ++i) Ws4[t + 256 * i] = Wg4[t + 256 * i];
    }

    const int dg = t & 31;
    const int ng = t >> 5;
    const int stride = (int)gridDim.y * GNB;
    const float4 bv = *(const float4*)&be[e * 128 + 4 * dg];
    const float4* __restrict__ Wv = (const float4*)Ws;
    const float4* __restrict__ Xv = (const float4*)xsd;

    // prefetch chunk 0 into registers (half-wave reads are 512 B contiguous)
    float4 xr[8];
    #pragma unroll
    for (int i = 0; i < 8; ++i) {
        const int id = t + 256 * i;
        const int idx = start + (id >> 5);
        const int node = elist[idx < row1 ? idx : start];
        xr[i] = ((const float4*)(x + (size_t)node * 128))[id & 31];
    }

    while (true) {
        // commit prefetched x to LDS (conflict-free: consecutive float4/half-wave)
        #pragma unroll
        for (int i = 0; i < 8; ++i) {
            const int id = t + 256 * i;
            ((float4*)xsd)[(id >> 5) * 32 + (id & 31)] = xr[i];
        }
        __syncthreads();   // orders W-stage (1st iter) + x commit before compute

        // issue next chunk's loads now; they fly under the compute below
        const int nstart = start + stride;
        const bool nhave = (nstart < row1);   // uniform
        if (nhave) {
            #pragma unroll
            for (int i = 0; i < 8; ++i) {
                const int id = t + 256 * i;
                const int idx = nstart + (id >> 5);
                const int node = elist[idx < row1 ? idx : nstart];
                xr[i] = ((const float4*)(x + (size_t)node * 128))[id & 31];
            }
        }

        float4 acc[8];
        #pragma unroll
        for (int k = 0; k < 8; ++k) acc[k] = bv;  // bias-init (matches baseline order)

        #pragma unroll 2
        for (int d4 = 0; d4 < 32; ++d4) {
            const float4 w0 = Wv[(4 * d4 + 0) * 32 + dg];
            const float4 w1 = Wv[(4 * d4 + 1) * 32 + dg];
            const float4 w2 = Wv[(4 * d4 + 2) * 32 + dg];
            const float4 w3 = Wv[(4 * d4 + 3) * 32 + dg];
            #pragma unroll
            for (int k = 0; k < 8; ++k) {
                const float4 xv = Xv[(8 * ng + k) * 32 + d4];
                acc[k].x = fmaf(xv.x, w0.x, acc[k].x);
                acc[k].y = fmaf(xv.x, w0.y, acc[k].y);
                acc[k].z = fmaf(xv.x, w0.z, acc[k].z);
                acc[k].w = fmaf(xv.x, w0.w, acc[k].w);
                acc[k].x = fmaf(xv.y, w1.x, acc[k].x);
                acc[k].y = fmaf(xv.y, w1.y, acc[k].y);
                acc[k].z = fmaf(xv.y, w1.z, acc[k].z);
                acc[k].w = fmaf(xv.y, w1.w, acc[k].w);
                acc[k].x = fmaf(xv.z, w2.x, acc[k].x);
                acc[k].y = fmaf(xv.z, w2.y, acc[k].y);
                acc[k].z = fmaf(xv.z, w2.z, acc[k].z);
                acc[k].w = fmaf(xv.z, w2.w, acc[k].w);
                acc[k].x = fmaf(xv.w, w3.x, acc[k].x);
                acc[k].y = fmaf(xv.w, w3.y, acc[k].y);
                acc[k].z = fmaf(xv.w, w3.z, acc[k].z);
                acc[k].w = fmaf(xv.w, w3.w, acc[k].w);
            }
        }

        #pragma unroll
        for (int k = 0; k < 8; ++k) {
            const int idx = start + 8 * ng + k;
            if (idx < row1)
                *(float4*)&y[(size_t)elist[idx] * 128 + 4 * dg] = acc[k];
        }

        if (!nhave) break;       // uniform
        __syncthreads();         // xsd fully consumed; safe to overwrite
        start = nstart;
    }
}

// ---------------- final plain linear 128 -> 64, 8 nodes/block ----------------
__global__ __launch_bounds__(64) void last_kernel(
    const float* __restrict__ h, const float* __restrict__ W, float* __restrict__ y)
{
    __shared__ float xs[NB][128];
    const int n0 = blockIdx.x * NB, t = threadIdx.x;
    #pragma unroll
    for (int j = 0; j < NB; ++j) {
        xs[j][t] = h[(size_t)(n0 + j) * 128 + t];
        xs[j][t + 64] = h[(size_t)(n0 + j) * 128 + t + 64];
    }
    __syncthreads();
    float a0 = 0.f, a1 = 0.f, a2 = 0.f, a3 = 0.f;
    float a4 = 0.f, a5 = 0.f, a6 = 0.f, a7 = 0.f;
    #pragma unroll 4
    for (int d = 0; d < 128; ++d) {
        const float w = W[d * 64 + t];
        a0 = fmaf(xs[0][d], w, a0);
        a1 = fmaf(xs[1][d], w, a1);
        a2 = fmaf(xs[2][d], w, a2);
        a3 = fmaf(xs[3][d], w, a3);
        a4 = fmaf(xs[4][d], w, a4);
        a5 = fmaf(xs[5][d], w, a5);
        a6 = fmaf(xs[6][d], w, a6);
        a7 = fmaf(xs[7][d], w, a7);
    }
    y[(size_t)(n0 + 0) * 64 + t] = a0;
    y[(size_t)(n0 + 1) * 64 + t] = a1;
    y[(size_t)(n0 + 2) * 64 + t] = a2;
    y[(size_t)(n0 + 3) * 64 + t] = a3;
    y[(size_t)(n0 + 4) * 64 + t] = a4;
    y[(size_t)(n0 + 5) * 64 + t] = a5;
    y[(size_t)(n0 + 6) * 64 + t] = a6;
    y[(size_t)(n0 + 7) * 64 + t] = a7;
}

// ---------------- CSR build: histogram -> scan -> fill -----------------------
__global__ void hist_kernel(const int* __restrict__ edst, int* __restrict__ cnt)
{
    const int i = blockIdx.x * blockDim.x + threadIdx.x;
    if (i < N_EDGES) atomicAdd(&cnt[edst[i]], 1);
}

__global__ __launch_bounds__(1024) void scan_kernel(
    const int* __restrict__ cnt, int* __restrict__ rowptr, int* __restrict__ cursor)
{
    __shared__ int buf[1024];
    __shared__ int carry_s;
    const int t = threadIdx.x;
    if (t == 0) carry_s = 0;
    __syncthreads();
    for (int base = 0; base < N_NODES; base += 1024) {
        const int i = base + t;
        const int v = (i < N_NODES) ? cnt[i] : 0;
        buf[t] = v;
        __syncthreads();
        for (int off = 1; off < 1024; off <<= 1) {
            const int add = (t >= off) ? buf[t - off] : 0;
            __syncthreads();
            buf[t] += add;
            __syncthreads();
        }
        const int excl = buf[t] - v + carry_s;
        if (i < N_NODES) { rowptr[i] = excl; cursor[i] = excl; }
        const int total = buf[1023];
        __syncthreads();
        if (t == 0) carry_s += total;
        __syncthreads();
    }
    if (t == 0) rowptr[N_NODES] = carry_s;
}

__global__ void fill_kernel(const int* __restrict__ esrc, const int* __restrict__ edst,
                            int* __restrict__ cursor, int* __restrict__ csr_src)
{
    const int i = blockIdx.x * blockDim.x + threadIdx.x;
    if (i < N_EDGES) {
        const int p = atomicAdd(&cursor[edst[i]], 1);
        csr_src[p] = esrc[i];
    }
}

// ---------------- gather aggregation: out[n] = bias + sum_{e in row n} h[src] -
template <int D, bool RELU>
__global__ __launch_bounds__(D) void gather_kernel(
    const float* __restrict__ h, const int* __restrict__ rowptr,
    const int* __restrict__ csr_src, const float* __restrict__ bias,
    float* __restrict__ out)
{
    const int n = blockIdx.x, t = threadIdx.x;
    const int s0 = rowptr[n], s1 = rowptr[n + 1];
    float a0 = bias[t], a1 = 0.f, a2 = 0.f, a3 = 0.f;
    int e = s0;
    for (; e + 3 < s1; e += 4) {
        const int i0 = csr_src[e + 0];
        const int i1 = csr_src[e + 1];
        const int i2 = csr_src[e + 2];
        const int i3 = csr_src[e + 3];
        a0 += h[(size_t)i0 * D + t];
        a1 += h[(size_t)i1 * D + t];
        a2 += h[(size_t)i2 * D + t];
        a3 += h[(size_t)i3 * D + t];
    }
    for (; e < s1; ++e) a0 += h[(size_t)csr_src[e] * D + t];
    float acc = (a0 + a1) + (a2 + a3);
    if (RELU) acc = fmaxf(acc, 0.f);
    out[(size_t)n * D + t] = acc;
}

// ---------------- finalize: reduce 2*NGBLK gate partials + write tail --------
__global__ __launch_bounds__(1024) void finalize_kernel(
    const float* __restrict__ gpart, float* __restrict__ out_tail)
{
    __shared__ float wsum[16];
    const int t = threadIdx.x;
    float s = 0.f;
    for (int i = t; i < 2 * NGBLK; i += 1024) s += gpart[i];
    #pragma unroll
    for (int m = 32; m >= 1; m >>= 1) s += __shfl_xor(s, m, 64);
    if ((t & 63) == 0) wsum[t >> 6] = s;
    __syncthreads();
    if (t == 0) {
        float tot = 0.f;
        #pragma unroll
        for (int w = 0; w < 16; ++w) tot += wsum[w];
        out_tail[0] = tot * (0.5f / (float)N_NODES);
        out_tail[1] = 1.0f;
    }
}

extern "C" void kernel_launch(void* const* d_in, const int* in_sizes, int n_in,
                              void* d_out, int out_size, void* d_ws, size_t ws_size,
                              hipStream_t stream)
{
    const float* x     = (const float*)d_in[0];
    const int*   edge  = (const int*)d_in[1];
    const float* Wg1   = (const float*)d_in[2];
    const float* bg1   = (const float*)d_in[3];
    const float* We1   = (const float*)d_in[4];
    const float* be1   = (const float*)d_in[5];
    const float* b1    = (const float*)d_in[6];
    const float* Wg2   = (const float*)d_in[7];
    const float* bg2   = (const float*)d_in[8];
    const float* We2   = (const float*)d_in[9];
    const float* be2   = (const float*)d_in[10];
    const float* b2    = (const float*)d_in[11];
    const float* Wlast = (const float*)d_in[12];
    const float* blast = (const float*)d_in[13];
    float* out = (float*)d_out;

    const int* esrc = edge;
    const int* edst = edge + N_EDGES;

    char* ws = (char*)d_ws;
    size_t off = 0;
    float* gpart = (float*)(ws + off); off += (size_t)2 * NGBLK * 4 + 252; off &= ~(size_t)255;
    float* A = (float*)(ws + off); off += (size_t)N_NODES * 128 * 4;
    float* B = (float*)(ws + off); off += (size_t)N_NODES * 128 * 4;
    int* rowptr = (int*)(ws + off); off += (size_t)(N_NODES + 1) * 4 + 252; off &= ~(size_t)255;
    int* cnt = (int*)(ws + off); off += (size_t)N_NODES * 4 + 252; off &= ~(size_t)255;
    int* csr_src = (int*)(ws + off); off += (size_t)N_EDGES * 4;
    int* elist = (int*)(ws + off); off += (size_t)N_NODES * 4 + 252; off &= ~(size_t)255;
    int* meta = (int*)(ws + off); off += 256;
    int* ecnt = meta;          // 16
    int* eoff = meta + 16;     // 17
    int* ecur = meta + 33;     // 16
    int* eidx = cnt;           // cnt is free after fill_kernel

    // ---- CSR build ----
    hipMemsetAsync(cnt, 0, (size_t)N_NODES * 4, stream);
    hist_kernel<<<(N_EDGES + 255) / 256, 256, 0, stream>>>(edst, cnt);
    scan_kernel<<<1, 1024, 0, stream>>>(cnt, rowptr, cnt);   // cursor aliases cnt
    fill_kernel<<<(N_EDGES + 255) / 256, 256, 0, stream>>>(esrc, edst, cnt, csr_src);

    const int nbk = (N_NODES + 255) / 256;

    // ---- layer 1 ----
    gate_kernel<<<NGBLK, 128, 0, stream>>>(x, Wg1, bg1, eidx, gpart);
    hipMemsetAsync(ecnt, 0, 64, stream);
    hist16_kernel<<<nbk, 256, 0, stream>>>(eidx, ecnt);
    scan16_kernel<<<1, 64, 0, stream>>>(ecnt, eoff, ecur);
    scatter16_kernel<<<nbk, 256, 0, stream>>>(eidx, ecur, elist);
    expert_gemm_kernel<<<dim3(N_EXPERT, NYB), 256, 0, stream>>>(x, We1, be1, eoff, elist, A);
    gather_kernel<128, true><<<N_NODES, 128, 0, stream>>>(A, rowptr, csr_src, b1, B);

    // ---- layer 2 ----
    gate_kernel<<<NGBLK, 128, 0, stream>>>(B, Wg2, bg2, eidx, gpart + NGBLK);
    hipMemsetAsync(ecnt, 0, 64, stream);
    hist16_kernel<<<nbk, 256, 0, stream>>>(eidx, ecnt);
    scan16_kernel<<<1, 64, 0, stream>>>(ecnt, eoff, ecur);
    scatter16_kernel<<<nbk, 256, 0, stream>>>(eidx, ecur, elist);
    expert_gemm_kernel<<<dim3(N_EXPERT, NYB), 256, 0, stream>>>(B, We2, be2, eoff, elist, A);
    gather_kernel<128, true><<<N_NODES, 128, 0, stream>>>(A, rowptr, csr_src, b2, B);

    // ---- layer 3 (plain GCNConv) ----
    last_kernel<<<N_NODES / NB, 64, 0, stream>>>(B, Wlast, A);
    gather_kernel<64, false><<<N_NODES, 64, 0, stream>>>(A, rowptr, csr_src, blast, out);

    finalize_kernel<<<1, 1024, 0, stream>>>(gpart, out + (size_t)N_NODES * 64);
}

// Round 6
// 810.129 us; speedup vs baseline: 1.0368x; 1.0368x over previous
//
#include <hip/hip_runtime.h>
#include <math.h>

#define N_NODES 50000
#define N_EDGES 1600000
#define D_IN 128
#define D_HID 128
#define D_OUT 64
#define N_EXPERT 16
#define NB 8    // nodes per block in gate/last kernels (50000 % 8 == 0)
#define GNB 64  // nodes per chunk in expert GEMM
#define NYB 256 // chunk-slots per expert (stride loop handles any skew)
#define NGBLK (N_NODES / NB)   // 6250 gate blocks per layer

// ---------------- gate: logits + softmax-std + argmax ------------------------
// One block = 128 threads = NB(8) nodes. Thread (e = t&15, j = t>>4).
// Wg staged TRANSPOSED in LDS (wgt[e][d], +4 pad) so the matvec is float4 LDS
// reads instead of a 16-distinct-address L1 scatter per wave-load.
__global__ __launch_bounds__(128) void gate_kernel(
    const float* __restrict__ x, const float* __restrict__ Wg, const float* __restrict__ bg,
    int* __restrict__ eidx, float* __restrict__ gpart)
{
    __shared__ float xs[NB][132];            // +4 pad: j-groups in disjoint banks
    __shared__ float wgt[N_EXPERT][132];     // transposed gate weights, +4 pad
    __shared__ float sred[NB];
    const int n0 = blockIdx.x * NB;
    const int t = threadIdx.x;

    #pragma unroll
    for (int i = t; i < 2048; i += 128)      // Wg[d*16+e] -> wgt[e][d]
        wgt[i & 15][i >> 4] = Wg[i];
    #pragma unroll
    for (int j = 0; j < NB; ++j)
        xs[j][t] = x[(size_t)(n0 + j) * 128 + t];
    __syncthreads();

    const int e = t & 15, j = t >> 4;
    float lg = bg[e];
    #pragma unroll
    for (int d4 = 0; d4 < 32; ++d4) {        // d-ascending FMA order preserved
        const float4 xv = *(const float4*)&xs[j][4 * d4];
        const float4 wv = *(const float4*)&wgt[e][4 * d4];
        lg = fmaf(xv.x, wv.x, lg);
        lg = fmaf(xv.y, wv.y, lg);
        lg = fmaf(xv.z, wv.z, lg);
        lg = fmaf(xv.w, wv.w, lg);
    }

    // 16-lane-group reductions (lanes of one node are contiguous)
    float mx = lg;
    #pragma unroll
    for (int m = 8; m >= 1; m >>= 1) mx = fmaxf(mx, __shfl_xor(mx, m, 16));
    const float ex = expf(lg - mx);
    float se = ex;
    #pragma unroll
    for (int m = 8; m >= 1; m >>= 1) se += __shfl_xor(se, m, 16);
    const float p = ex / se;
    const float dm = p - (1.f / 16.f);
    float var = dm * dm;
    #pragma unroll
    for (int m = 8; m >= 1; m >>= 1) var += __shfl_xor(var, m, 16);

    // argmax over logits (== argmax over softmax), first-index on ties
    float bv = lg; int bi = e;
    #pragma unroll
    for (int m = 8; m >= 1; m >>= 1) {
        const float ov = __shfl_xor(bv, m, 16);
        const int oi = __shfl_xor(bi, m, 16);
        if (ov > bv || (ov == bv && oi < bi)) { bv = ov; bi = oi; }
    }
    if (e == 0) {
        eidx[n0 + j] = bi;
        sred[j] = sqrtf(var * (1.f / 15.f));
    }
    __syncthreads();
    if (t == 0) {
        float s = 0.f;
        #pragma unroll
        for (int jj = 0; jj < NB; ++jj) s += sred[jj];
        gpart[blockIdx.x] = s;
    }
}

// ---------------- expert bucketing: hist16 -> scan16 -> scatter16 ------------
__global__ __launch_bounds__(256) void hist16_kernel(
    const int* __restrict__ eidx, int* __restrict__ ecnt)
{
    __shared__ int lcnt[N_EXPERT];
    const int t = threadIdx.x;
    const int n = blockIdx.x * 256 + t;
    if (t < N_EXPERT) lcnt[t] = 0;
    __syncthreads();
    if (n < N_NODES) atomicAdd(&lcnt[eidx[n]], 1);
    __syncthreads();
    if (t < N_EXPERT && lcnt[t] > 0) atomicAdd(&ecnt[t], lcnt[t]);
}

__global__ void scan16_kernel(const int* __restrict__ ecnt,
                              int* __restrict__ eoff, int* __restrict__ ecur)
{
    if (threadIdx.x == 0) {
        int s = 0;
        #pragma unroll
        for (int e = 0; e < N_EXPERT; ++e) { eoff[e] = s; ecur[e] = s; s += ecnt[e]; }
        eoff[N_EXPERT] = s;
    }
}

__global__ __launch_bounds__(256) void scatter16_kernel(
    const int* __restrict__ eidx, int* __restrict__ ecur, int* __restrict__ elist)
{
    __shared__ int lcnt[N_EXPERT];
    __shared__ int lbase[N_EXPERT];
    const int t = threadIdx.x;
    const int n = blockIdx.x * 256 + t;
    if (t < N_EXPERT) lcnt[t] = 0;
    __syncthreads();
    int e = 0, lpos = 0;
    if (n < N_NODES) { e = eidx[n]; lpos = atomicAdd(&lcnt[e], 1); }
    __syncthreads();
    if (t < N_EXPERT && lcnt[t] > 0) lbase[t] = atomicAdd(&ecur[t], lcnt[t]);
    __syncthreads();
    if (n < N_NODES) elist[lbase[e] + lpos] = n;
}

// ---------------- per-expert GEMM: y[n] = x[n] @ We[e] + be[e] ---------------
// grid = (16 experts, NYB=256 chunk-slots) with a CHUNK-STRIDE loop: capacity
// is unbounded, so arbitrarily skewed gating (layer 2 collapses onto few
// experts!) is handled. Empty slots exit immediately.
// NO W LDS stage: W streams from L2 as coalesced float4 (multicast across
// waves/blocks). Only the 64-node x chunk is in LDS (32 KB) -> 3 blocks/CU.
// Thread tile: (dgg = t&15 -> dims 8dgg..8dgg+7, ngg = t>>4 -> nodes 4ngg..+3).
__global__ __launch_bounds__(256, 3) void expert_gemm_kernel(
    const float* __restrict__ x, const float* __restrict__ We, const float* __restrict__ be,
    const int* __restrict__ eoff, const int* __restrict__ elist, float* __restrict__ y)
{
    __shared__ float xsd[GNB * 128];  // 32 KB
    const int e = blockIdx.x;
    const int t = threadIdx.x;
    const int row0 = eoff[e];
    const int row1 = eoff[e + 1];

    const int dgg = t & 15;   // dims 8*dgg .. 8*dgg+7
    const int ngg = t >> 4;   // nodes 4*ngg .. 4*ngg+3
    const float4* __restrict__ Wv = (const float4*)(We + (size_t)e * 16384);
    const float4* __restrict__ Xv = (const float4*)xsd;
    const float4 b0 = *(const float4*)&be[e * 128 + 8 * dgg];
    const float4 b1 = *(const float4*)&be[e * 128 + 8 * dgg + 4];

    for (int chunk = blockIdx.y;; chunk += (int)gridDim.y) {
        const int start = row0 + chunk * GNB;
        if (start >= row1) break;   // block-uniform

        // stage 64 node rows of x (float4, coalesced; dummy = first node)
        #pragma unroll
        for (int i = 0; i < 8; ++i) {
            const int id = t + 256 * i;
            const int n = id >> 5;
            const int d4 = id & 31;
            const int idx = start + n;
            const int node = elist[idx < row1 ? idx : start];
            ((float4*)xsd)[n * 32 + d4] = ((const float4*)(x + (size_t)node * 128))[d4];
        }
        __syncthreads();

        float4 acc[4][2];
        #pragma unroll
        for (int k = 0; k < 4; ++k) { acc[k][0] = b0; acc[k][1] = b1; }

        #pragma unroll 2
        for (int d4 = 0; d4 < 32; ++d4) {
            float4 w[4][2];   // W rows 4d4..4d4+3, this thread's 8 dims
            #pragma unroll
            for (int r = 0; r < 4; ++r) {
                w[r][0] = Wv[(4 * d4 + r) * 32 + 2 * dgg];
                w[r][1] = Wv[(4 * d4 + r) * 32 + 2 * dgg + 1];
            }
            #pragma unroll
            for (int k = 0; k < 4; ++k) {
                const float4 xv = Xv[(4 * ngg + k) * 32 + d4];
                const float xa[4] = {xv.x, xv.y, xv.z, xv.w};
                #pragma unroll
                for (int r = 0; r < 4; ++r) {   // d ascending -> baseline order
                    acc[k][0].x = fmaf(xa[r], w[r][0].x, acc[k][0].x);
                    acc[k][0].y = fmaf(xa[r], w[r][0].y, acc[k][0].y);
                    acc[k][0].z = fmaf(xa[r], w[r][0].z, acc[k][0].z);
                    acc[k][0].w = fmaf(xa[r], w[r][0].w, acc[k][0].w);
                    acc[k][1].x = fmaf(xa[r], w[r][1].x, acc[k][1].x);
                    acc[k][1].y = fmaf(xa[r], w[r][1].y, acc[k][1].y);
                    acc[k][1].z = fmaf(xa[r], w[r][1].z, acc[k][1].z);
                    acc[k][1].w = fmaf(xa[r], w[r][1].w, acc[k][1].w);
                }
            }
        }

        #pragma unroll
        for (int k = 0; k < 4; ++k) {
            const int idx = start + 4 * ngg + k;
            if (idx < row1) {
                float* yp = &y[(size_t)elist[idx] * 128 + 8 * dgg];
                *(float4*)yp = acc[k][0];
                *(float4*)(yp + 4) = acc[k][1];
            }
        }

        __syncthreads();   // xsd fully consumed before next-chunk restage
    }
}

// ---------------- final plain linear 128 -> 64, 8 nodes/block ----------------
__global__ __launch_bounds__(64) void last_kernel(
    const float* __restrict__ h, const float* __restrict__ W, float* __restrict__ y)
{
    __shared__ float xs[NB][128];
    const int n0 = blockIdx.x * NB, t = threadIdx.x;
    #pragma unroll
    for (int j = 0; j < NB; ++j) {
        xs[j][t] = h[(size_t)(n0 + j) * 128 + t];
        xs[j][t + 64] = h[(size_t)(n0 + j) * 128 + t + 64];
    }
    __syncthreads();
    float a0 = 0.f, a1 = 0.f, a2 = 0.f, a3 = 0.f;
    float a4 = 0.f, a5 = 0.f, a6 = 0.f, a7 = 0.f;
    #pragma unroll 4
    for (int d = 0; d < 128; ++d) {
        const float w = W[d * 64 + t];
        a0 = fmaf(xs[0][d], w, a0);
        a1 = fmaf(xs[1][d], w, a1);
        a2 = fmaf(xs[2][d], w, a2);
        a3 = fmaf(xs[3][d], w, a3);
        a4 = fmaf(xs[4][d], w, a4);
        a5 = fmaf(xs[5][d], w, a5);
        a6 = fmaf(xs[6][d], w, a6);
        a7 = fmaf(xs[7][d], w, a7);
    }
    y[(size_t)(n0 + 0) * 64 + t] = a0;
    y[(size_t)(n0 + 1) * 64 + t] = a1;
    y[(size_t)(n0 + 2) * 64 + t] = a2;
    y[(size_t)(n0 + 3) * 64 + t] = a3;
    y[(size_t)(n0 + 4) * 64 + t] = a4;
    y[(size_t)(n0 + 5) * 64 + t] = a5;
    y[(size_t)(n0 + 6) * 64 + t] = a6;
    y[(size_t)(n0 + 7) * 64 + t] = a7;
}

// ---------------- CSR build: histogram -> scan -> fill -----------------------
__global__ void hist_kernel(const int* __restrict__ edst, int* __restrict__ cnt)
{
    const int i = blockIdx.x * blockDim.x + threadIdx.x;
    if (i < N_EDGES) atomicAdd(&cnt[edst[i]], 1);
}

// Single-block scan, hoisted: per-thread serial sum (49 entries) -> one
// 1024-wide Hillis-Steele -> serial write-back. cursor is a SEPARATE buffer.
__global__ __launch_bounds__(1024) void scan_kernel(
    const int* __restrict__ cnt, int* __restrict__ rowptr, int* __restrict__ cursor)
{
    __shared__ int buf[1024];
    const int t = threadIdx.x;
    const int base = t * 49;               // 49*1024 = 50176 >= N_NODES
    int s = 0;
    for (int i = 0; i < 49; ++i) {
        const int idx = base + i;
        if (idx < N_NODES) s += cnt[idx];
    }
    buf[t] = s;
    __syncthreads();
    for (int off = 1; off < 1024; off <<= 1) {
        const int add = (t >= off) ? buf[t - off] : 0;
        __syncthreads();
        buf[t] += add;
        __syncthreads();
    }
    int run = buf[t] - s;                  // exclusive prefix of this chunk
    for (int i = 0; i < 49; ++i) {
        const int idx = base + i;
        if (idx < N_NODES) {
            const int c = cnt[idx];
            rowptr[idx] = run; cursor[idx] = run;
            run += c;
        }
    }
    if (t == 1023) rowptr[N_NODES] = run;  // total edges
}

__global__ void fill_kernel(const int* __restrict__ esrc, const int* __restrict__ edst,
                            int* __restrict__ cursor, int* __restrict__ csr_src)
{
    const int i = blockIdx.x * blockDim.x + threadIdx.x;
    if (i < N_EDGES) {
        const int p = atomicAdd(&cursor[edst[i]], 1);
        csr_src[p] = esrc[i];
    }
}

// ---------------- gather aggregation: out[n] = bias + sum_{e in row n} h[src] -
template <int D, bool RELU>
__global__ __launch_bounds__(D) void gather_kernel(
    const float* __restrict__ h, const int* __restrict__ rowptr,
    const int* __restrict__ csr_src, const float* __restrict__ bias,
    float* __restrict__ out)
{
    const int n = blockIdx.x, t = threadIdx.x;
    const int s0 = rowptr[n], s1 = rowptr[n + 1];
    float a0 = bias[t], a1 = 0.f, a2 = 0.f, a3 = 0.f;
    int e = s0;
    for (; e + 3 < s1; e += 4) {
        const int i0 = csr_src[e + 0];
        const int i1 = csr_src[e + 1];
        const int i2 = csr_src[e + 2];
        const int i3 = csr_src[e + 3];
        a0 += h[(size_t)i0 * D + t];
        a1 += h[(size_t)i1 * D + t];
        a2 += h[(size_t)i2 * D + t];
        a3 += h[(size_t)i3 * D + t];
    }
    for (; e < s1; ++e) a0 += h[(size_t)csr_src[e] * D + t];
    float acc = (a0 + a1) + (a2 + a3);
    if (RELU) acc = fmaxf(acc, 0.f);
    out[(size_t)n * D + t] = acc;
}

// ---------------- finalize: reduce 2*NGBLK gate partials + write tail --------
__global__ __launch_bounds__(1024) void finalize_kernel(
    const float* __restrict__ gpart, float* __restrict__ out_tail)
{
    __shared__ float wsum[16];
    const int t = threadIdx.x;
    float s = 0.f;
    for (int i = t; i < 2 * NGBLK; i += 1024) s += gpart[i];
    #pragma unroll
    for (int m = 32; m >= 1; m >>= 1) s += __shfl_xor(s, m, 64);
    if ((t & 63) == 0) wsum[t >> 6] = s;
    __syncthreads();
    if (t == 0) {
        float tot = 0.f;
        #pragma unroll
        for (int w = 0; w < 16; ++w) tot += wsum[w];
        out_tail[0] = tot * (0.5f / (float)N_NODES);
        out_tail[1] = 1.0f;
    }
}

extern "C" void kernel_launch(void* const* d_in, const int* in_sizes, int n_in,
                              void* d_out, int out_size, void* d_ws, size_t ws_size,
                              hipStream_t stream)
{
    const float* x     = (const float*)d_in[0];
    const int*   edge  = (const int*)d_in[1];
    const float* Wg1   = (const float*)d_in[2];
    const float* bg1   = (const float*)d_in[3];
    const float* We1   = (const float*)d_in[4];
    const float* be1   = (const float*)d_in[5];
    const float* b1    = (const float*)d_in[6];
    const float* Wg2   = (const float*)d_in[7];
    const float* bg2   = (const float*)d_in[8];
    const float* We2   = (const float*)d_in[9];
    const float* be2   = (const float*)d_in[10];
    const float* b2    = (const float*)d_in[11];
    const float* Wlast = (const float*)d_in[12];
    const float* blast = (const float*)d_in[13];
    float* out = (float*)d_out;

    const int* esrc = edge;
    const int* edst = edge + N_EDGES;

    char* ws = (char*)d_ws;
    size_t off = 0;
    float* gpart = (float*)(ws + off); off += (size_t)2 * NGBLK * 4 + 252; off &= ~(size_t)255;
    float* A = (float*)(ws + off); off += (size_t)N_NODES * 128 * 4;
    float* B = (float*)(ws + off); off += (size_t)N_NODES * 128 * 4;
    int* rowptr = (int*)(ws + off); off += (size_t)(N_NODES + 1) * 4 + 252; off &= ~(size_t)255;
    int* cnt = (int*)(ws + off); off += (size_t)N_NODES * 4 + 252; off &= ~(size_t)255;
    int* cursor = (int*)(ws + off); off += (size_t)N_NODES * 4 + 252; off &= ~(size_t)255;
    int* csr_src = (int*)(ws + off); off += (size_t)N_EDGES * 4;
    int* elist = (int*)(ws + off); off += (size_t)N_NODES * 4 + 252; off &= ~(size_t)255;
    int* meta = (int*)(ws + off); off += 256;
    int* ecnt = meta;          // 16
    int* eoff = meta + 16;     // 17
    int* ecur = meta + 33;     // 16
    int* eidx = cnt;           // cnt is free after scan_kernel

    // ---- CSR build ----
    hipMemsetAsync(cnt, 0, (size_t)N_NODES * 4, stream);
    hist_kernel<<<(N_EDGES + 255) / 256, 256, 0, stream>>>(edst, cnt);
    scan_kernel<<<1, 1024, 0, stream>>>(cnt, rowptr, cursor);
    fill_kernel<<<(N_EDGES + 255) / 256, 256, 0, stream>>>(esrc, edst, cursor, csr_src);

    const int nbk = (N_NODES + 255) / 256;

    // ---- layer 1 ----
    gate_kernel<<<NGBLK, 128, 0, stream>>>(x, Wg1, bg1, eidx, gpart);
    hipMemsetAsync(ecnt, 0, 64, stream);
    hist16_kernel<<<nbk, 256, 0, stream>>>(eidx, ecnt);
    scan16_kernel<<<1, 64, 0, stream>>>(ecnt, eoff, ecur);
    scatter16_kernel<<<nbk, 256, 0, stream>>>(eidx, ecur, elist);
    expert_gemm_kernel<<<dim3(N_EXPERT, NYB), 256, 0, stream>>>(x, We1, be1, eoff, elist, A);
    gather_kernel<128, true><<<N_NODES, 128, 0, stream>>>(A, rowptr, csr_src, b1, B);

    // ---- layer 2 ----
    gate_kernel<<<NGBLK, 128, 0, stream>>>(B, Wg2, bg2, eidx, gpart + NGBLK);
    hipMemsetAsync(ecnt, 0, 64, stream);
    hist16_kernel<<<nbk, 256, 0, stream>>>(eidx, ecnt);
    scan16_kernel<<<1, 64, 0, stream>>>(ecnt, eoff, ecur);
    scatter16_kernel<<<nbk, 256, 0, stream>>>(eidx, ecur, elist);
    expert_gemm_kernel<<<dim3(N_EXPERT, NYB), 256, 0, stream>>>(B, We2, be2, eoff, elist, A);
    gather_kernel<128, true><<<N_NODES, 128, 0, stream>>>(A, rowptr, csr_src, b2, B);

    // ---- layer 3 (plain GCNConv) ----
    last_kernel<<<N_NODES / NB, 64, 0, stream>>>(B, Wlast, A);
    gather_kernel<64, false><<<N_NODES, 64, 0, stream>>>(A, rowptr, csr_src, blast, out);

    finalize_kernel<<<1, 1024, 0, stream>>>(gpart, out + (size_t)N_NODES * 64);
}